// Round 1
// baseline (143.294 us; speedup 1.0000x reference)
//
#include <hip/hip_runtime.h>
#include <math.h>

#define LOG2E 1.4426950408889634f

__device__ __forceinline__ float fast_exp2(float x) {
#if defined(__has_builtin)
#if __has_builtin(__builtin_amdgcn_exp2f)
    return __builtin_amdgcn_exp2f(x);
#else
    return exp2f(x);
#endif
#else
    return exp2f(x);
#endif
}

// ---------------------------------------------------------------------------
// K1: y1[b,o,p] = sum_c x[b,c,p]*w_sq1[o,c] + b_sq1[o]
// x: (2,64,64,64), y1: (2,32,4096). Block: 64 pixels x 4 o-groups (8 o each).
// ---------------------------------------------------------------------------
__global__ __launch_bounds__(256) void k_conv_sq1(const float* __restrict__ x,
        const float* __restrict__ w, const float* __restrict__ bias,
        float* __restrict__ y1) {
    __shared__ float lx[64 * 64];   // [c][px]
    __shared__ float lw[32 * 64];   // [o][c]
    int tid = threadIdx.x;
    int gp0 = blockIdx.x * 64;      // global pixel base (B*4096 total)
    int b   = gp0 >> 12;
    int p0  = gp0 & 4095;
    for (int idx = tid; idx < 64 * 64; idx += 256) {
        int c = idx >> 6, pp = idx & 63;
        lx[idx] = x[(b * 64 + c) * 4096 + p0 + pp];
    }
    for (int idx = tid; idx < 32 * 64; idx += 256) lw[idx] = w[idx];
    __syncthreads();
    int px = tid & 63, og = tid >> 6;
    float acc[8];
#pragma unroll
    for (int k = 0; k < 8; ++k) acc[k] = 0.f;
    for (int c = 0; c < 64; ++c) {
        float xv = lx[c * 64 + px];
#pragma unroll
        for (int k = 0; k < 8; ++k)
            acc[k] = fmaf(lw[(og * 8 + k) * 64 + c], xv, acc[k]);
    }
#pragma unroll
    for (int k = 0; k < 8; ++k) {
        int o = og * 8 + k;
        y1[(b * 32 + o) * 4096 + p0 + px] = acc[k] + bias[o];
    }
}

// ---------------------------------------------------------------------------
// K2: depthwise 2x2 stride-2 conv + channel permute idx[k] = (k>>1)+((k&1)<<5)
// y3[b,k,p32] = dwconv(y1)[b, idx[k], i, j];  y3: (2,64,1024)
// ---------------------------------------------------------------------------
__global__ __launch_bounds__(256) void k_dw_perm(const float* __restrict__ y1,
        const float* __restrict__ w2, const float* __restrict__ b2,
        float* __restrict__ y3) {
    int id = blockIdx.x * 256 + threadIdx.x;   // 131072 total
    int p32 = id & 1023;
    int k = (id >> 10) & 63;
    int b = id >> 16;
    int oc = (k >> 1) + ((k & 1) << 5);        // original channel after permute
    int g = oc >> 1;                           // depthwise group = y1 channel
    int i = p32 >> 5, j = p32 & 31;
    const float* src = y1 + (b * 32 + g) * 4096 + (i * 2) * 64 + j * 2;
    float v = b2[oc];
    v = fmaf(w2[oc * 4 + 0], src[0],  v);
    v = fmaf(w2[oc * 4 + 1], src[1],  v);
    v = fmaf(w2[oc * 4 + 2], src[64], v);
    v = fmaf(w2[oc * 4 + 3], src[65], v);
    y3[id] = v;                                // id == (b*64+k)*1024 + p32
}

// ---------------------------------------------------------------------------
// K3: channel attention (spatial=False) collapsed to per-pair linear map.
// For pair j (channels 2j,2j+1): all q/k norms+dots derive from Gram stats
// (S00,S01,S11,M0,M1) over n=1024. Output y4[c] = A*x0 + B*x1 + C.
// Grid: 64 blocks = (b, j).
// ---------------------------------------------------------------------------
__global__ __launch_bounds__(256) void k_chan_attn(const float* __restrict__ y3,
        const float* __restrict__ wqkv, const float* __restrict__ bqkv,
        const float* __restrict__ t,    const float* __restrict__ wf,
        const float* __restrict__ bfuse, float* __restrict__ y4) {
    int tid = threadIdx.x;
    int b = blockIdx.x >> 5, j = blockIdx.x & 31;
    const float* p0 = y3 + (b * 64 + 2 * j) * 1024;
    const float* p1 = p0 + 1024;
    float x0r[4], x1r[4];
    float s00 = 0, s01 = 0, s11 = 0, m0 = 0, m1 = 0;
#pragma unroll
    for (int r = 0; r < 4; ++r) {
        int n = tid + r * 256;
        float a = p0[n], c = p1[n];
        x0r[r] = a; x1r[r] = c;
        s00 = fmaf(a, a, s00); s01 = fmaf(a, c, s01); s11 = fmaf(c, c, s11);
        m0 += a; m1 += c;
    }
#pragma unroll
    for (int off = 1; off < 64; off <<= 1) {
        s00 += __shfl_xor(s00, off, 64);
        s01 += __shfl_xor(s01, off, 64);
        s11 += __shfl_xor(s11, off, 64);
        m0  += __shfl_xor(m0,  off, 64);
        m1  += __shfl_xor(m1,  off, 64);
    }
    __shared__ float red[5][4];
    int wid = tid >> 6;
    if ((tid & 63) == 0) {
        red[0][wid] = s00; red[1][wid] = s01; red[2][wid] = s11;
        red[3][wid] = m0;  red[4][wid] = m1;
    }
    __syncthreads();
    s00 = red[0][0] + red[0][1] + red[0][2] + red[0][3];
    s01 = red[1][0] + red[1][1] + red[1][2] + red[1][3];
    s11 = red[2][0] + red[2][1] + red[2][2] + red[2][3];
    m0  = red[3][0] + red[3][1] + red[3][2] + red[3][3];
    m1  = red[4][0] + red[4][1] + red[4][2] + red[4][3];

    const float N = 1024.f;
    int c0 = 2 * j, c1 = 2 * j + 1;
    float alpha[2][2], beta_[2][2], gamma_[2][2];   // [e][d]
#pragma unroll
    for (int e = 0; e < 2; ++e) {
        float wq0 = wqkv[c0 * 6 + e],     wq1 = wqkv[c1 * 6 + e];
        float bq0 = bqkv[c0 * 6 + e],     bq1 = bqkv[c1 * 6 + e];
        float wk0 = wqkv[c0 * 6 + 2 + e], wk1 = wqkv[c1 * 6 + 2 + e];
        float bk0 = bqkv[c0 * 6 + 2 + e], bk1 = bqkv[c1 * 6 + 2 + e];
        float wv0 = wqkv[c0 * 6 + 4 + e], wv1 = wqkv[c1 * 6 + 4 + e];
        float bv0 = bqkv[c0 * 6 + 4 + e], bv1 = bqkv[c1 * 6 + 4 + e];
        float te = t[e * 32 + j];
        // ||q_d||^2, ||k_d||^2
        float qq0 = wq0 * wq0 * s00 + 2.f * wq0 * bq0 * m0 + N * bq0 * bq0;
        float qq1 = wq1 * wq1 * s11 + 2.f * wq1 * bq1 * m1 + N * bq1 * bq1;
        float kk0 = wk0 * wk0 * s00 + 2.f * wk0 * bk0 * m0 + N * bk0 * bk0;
        float kk1 = wk1 * wk1 * s11 + 2.f * wk1 * bk1 * m1 + N * bk1 * bk1;
        float inq0 = 1.f / fmaxf(sqrtf(fmaxf(qq0, 0.f)), 1e-12f);
        float inq1 = 1.f / fmaxf(sqrtf(fmaxf(qq1, 0.f)), 1e-12f);
        float ink0 = 1.f / fmaxf(sqrtf(fmaxf(kk0, 0.f)), 1e-12f);
        float ink1 = 1.f / fmaxf(sqrtf(fmaxf(kk1, 0.f)), 1e-12f);
        // q_d . k_e2
        float qk00 = wq0 * wk0 * s00 + wq0 * bk0 * m0 + bq0 * wk0 * m0 + N * bq0 * bk0;
        float qk01 = wq0 * wk1 * s01 + wq0 * bk1 * m0 + bq0 * wk1 * m1 + N * bq0 * bk1;
        float qk10 = wq1 * wk0 * s01 + wq1 * bk0 * m1 + bq1 * wk0 * m0 + N * bq1 * bk0;
        float qk11 = wq1 * wk1 * s11 + wq1 * bk1 * m1 + bq1 * wk1 * m1 + N * bq1 * bk1;
        float L00 = qk00 * inq0 * ink0 * te, L01 = qk01 * inq0 * ink1 * te;
        float L10 = qk10 * inq1 * ink0 * te, L11 = qk11 * inq1 * ink1 * te;
        // 2-way softmax per row d
        float mx0 = fmaxf(L00, L01);
        float e00 = expf(L00 - mx0), e01 = expf(L01 - mx0);
        float iv0 = 1.f / (e00 + e01);
        float p00 = e00 * iv0, p01 = e01 * iv0;
        float mx1 = fmaxf(L10, L11);
        float e10 = expf(L10 - mx1), e11 = expf(L11 - mx1);
        float iv1 = 1.f / (e10 + e11);
        float p10 = e10 * iv1, p11 = e11 * iv1;
        alpha[e][0] = p00 * wv0; beta_[e][0] = p01 * wv1; gamma_[e][0] = p00 * bv0 + p01 * bv1;
        alpha[e][1] = p10 * wv0; beta_[e][1] = p11 * wv1; gamma_[e][1] = p10 * bv0 + p11 * bv1;
    }
    float A[2], B[2], C[2];
#pragma unroll
    for (int d = 0; d < 2; ++d) {
        int c = 2 * j + d;
        float f0 = wf[c * 2], f1 = wf[c * 2 + 1];
        A[d] = f0 * alpha[0][d] + f1 * alpha[1][d];
        B[d] = f0 * beta_[0][d] + f1 * beta_[1][d];
        C[d] = f0 * gamma_[0][d] + f1 * gamma_[1][d] + bfuse[c];
    }
    float* q0 = y4 + (b * 64 + 2 * j) * 1024;
    float* q1 = q0 + 1024;
#pragma unroll
    for (int r = 0; r < 4; ++r) {
        int n = tid + r * 256;
        q0[n] = fmaf(A[0], x0r[r], fmaf(B[0], x1r[r], C[0]));
        q1[n] = fmaf(A[1], x0r[r], fmaf(B[1], x1r[r], C[1]));
    }
}

// ---------------------------------------------------------------------------
// K5: spatial attention (spatial=True, rank-2 flash-style) with:
//   - nidx channel permute fused into the loads
//   - group fuse (wf/bf) + grouped 1x1 un1 + pixel shuffle fused into epilogue
// Grid: 512 blocks = (b:2, j:32, chunk:8); 256 thr = 128 n x 2 e.
// Writes y8: (2,32,64,64) (the pixel-shuffled un1 output).
// ---------------------------------------------------------------------------
__global__ __launch_bounds__(256) void k_spat_attn(const float* __restrict__ y4,
        const float* __restrict__ wqkv, const float* __restrict__ bqkv,
        const float* __restrict__ t,    const float* __restrict__ wf,
        const float* __restrict__ bfuse, const float* __restrict__ w1,
        const float* __restrict__ b1,   float* __restrict__ y8) {
    __shared__ float lx0[1024], lx1[1024];
    __shared__ float4 kv[2][1024];        // {k0*t*log2e, k1*t*log2e, v0, v1}
    __shared__ float ox[2][2][128];       // [e][d][nn]
    int tid = threadIdx.x;
    int chunk = blockIdx.x & 7;
    int j = (blockIdx.x >> 3) & 31;
    int b = blockIdx.x >> 8;
    int c0 = 2 * j, c1 = 2 * j + 1;
    // nidx[k] = (k>>5) + ((k&31)<<1)
    int src0 = (c0 >> 5) + ((c0 & 31) << 1);
    int src1 = (c1 >> 5) + ((c1 & 31) << 1);
    const float* px0 = y4 + (b * 64 + src0) * 1024;
    const float* px1 = y4 + (b * 64 + src1) * 1024;
    for (int idx = tid; idx < 1024; idx += 256) {
        lx0[idx] = px0[idx];
        lx1[idx] = px1[idx];
    }
    __syncthreads();
    // build k-hat (pre-scaled by t*log2e) and v arrays, both e
#pragma unroll
    for (int ee = 0; ee < 2; ++ee) {
        float wk0 = wqkv[c0 * 6 + 2 + ee], wk1 = wqkv[c1 * 6 + 2 + ee];
        float bk0 = bqkv[c0 * 6 + 2 + ee], bk1 = bqkv[c1 * 6 + 2 + ee];
        float wv0 = wqkv[c0 * 6 + 4 + ee], wv1 = wqkv[c1 * 6 + 4 + ee];
        float bv0 = bqkv[c0 * 6 + 4 + ee], bv1 = bqkv[c1 * 6 + 4 + ee];
        float tl = t[ee * 32 + j] * LOG2E;
        for (int m = tid; m < 1024; m += 256) {
            float a = lx0[m], c = lx1[m];
            float k0 = fmaf(wk0, a, bk0), k1 = fmaf(wk1, c, bk1);
            float nk = sqrtf(k0 * k0 + k1 * k1);
            float inv = 1.f / fmaxf(nk, 1e-12f);
            kv[ee][m] = make_float4(k0 * inv * tl, k1 * inv * tl,
                                    fmaf(wv0, a, bv0), fmaf(wv1, c, bv1));
        }
    }
    __syncthreads();
    int nn = tid & 127;
    int e  = tid >> 7;          // wave-uniform
    int n  = chunk * 128 + nn;
    float wq0 = wqkv[c0 * 6 + e], wq1 = wqkv[c1 * 6 + e];
    float bq0 = bqkv[c0 * 6 + e], bq1 = bqkv[c1 * 6 + e];
    float tt = t[e * 32 + j];
    float q0 = fmaf(wq0, lx0[n], bq0), q1 = fmaf(wq1, lx1[n], bq1);
    float nq = sqrtf(q0 * q0 + q1 * q1);
    float qinv = 1.f / fmaxf(nq, 1e-12f);
    float a = q0 * qinv, bb = q1 * qinv;
    float cbias = -fabsf(tt) * LOG2E;    // stable: arg = t*(S-1)*log2e <= 0
    float den = 0.f, o0 = 0.f, o1 = 0.f;
    const float4* kvp = kv[e];
#pragma unroll 4
    for (int m = 0; m < 1024; ++m) {
        float4 K = kvp[m];
        float arg = fmaf(a, K.x, fmaf(bb, K.y, cbias));
        float w = fast_exp2(arg);
        den += w;
        o0 = fmaf(w, K.z, o0);
        o1 = fmaf(w, K.w, o1);
    }
    float r = 1.f / den;
    ox[e][0][nn] = o0 * r;
    ox[e][1][nn] = o1 * r;
    __syncthreads();
    if (tid < 128) {
        int n2 = chunk * 128 + tid;
        // group fuse -> y6 channels 2j, 2j+1 at pixel n2
        float t0 = fmaf(wf[c0 * 2], ox[0][0][tid], fmaf(wf[c0 * 2 + 1], ox[1][0][tid], bfuse[c0]));
        float t1 = fmaf(wf[c1 * 2], ox[0][1][tid], fmaf(wf[c1 * 2 + 1], ox[1][1][tid], bfuse[c1]));
        // un1 (group j -> channels 4j..4j+3) + pixel shuffle
        int i32 = n2 >> 5, j32 = n2 & 31;
        float* dst = y8 + (b * 32 + j) * 4096 + (i32 * 2) * 64 + j32 * 2;
#pragma unroll
        for (int rr = 0; rr < 4; ++rr) {
            float z = fmaf(w1[(4 * j + rr) * 2], t0,
                      fmaf(w1[(4 * j + rr) * 2 + 1], t1, b1[4 * j + rr]));
            dst[(rr >> 1) * 64 + (rr & 1)] = z;
        }
    }
}

// ---------------------------------------------------------------------------
// K6: out[b,o,p] = sum_g w_un2[o,g]*y8[b,g,p] + b_un2[o];  (2,64,4096)
// ---------------------------------------------------------------------------
__global__ __launch_bounds__(256) void k_conv_un2(const float* __restrict__ y8,
        const float* __restrict__ w, const float* __restrict__ bias,
        float* __restrict__ out) {
    __shared__ float lx[32 * 64];   // [g][px]
    __shared__ float lw[64 * 32];   // [o][g]
    int tid = threadIdx.x;
    int gp0 = blockIdx.x * 64;
    int b = gp0 >> 12;
    int p0 = gp0 & 4095;
    for (int idx = tid; idx < 32 * 64; idx += 256) {
        int g = idx >> 6, pp = idx & 63;
        lx[idx] = y8[(b * 32 + g) * 4096 + p0 + pp];
    }
    for (int idx = tid; idx < 64 * 32; idx += 256) lw[idx] = w[idx];
    __syncthreads();
    int px = tid & 63, og = tid >> 6;   // 16 outputs each
    float acc[16];
#pragma unroll
    for (int k = 0; k < 16; ++k) acc[k] = 0.f;
    for (int g = 0; g < 32; ++g) {
        float xv = lx[g * 64 + px];
#pragma unroll
        for (int k = 0; k < 16; ++k)
            acc[k] = fmaf(lw[(og * 16 + k) * 32 + g], xv, acc[k]);
    }
#pragma unroll
    for (int k = 0; k < 16; ++k) {
        int o = og * 16 + k;
        out[(b * 64 + o) * 4096 + p0 + px] = acc[k] + bias[o];
    }
}

extern "C" void kernel_launch(void* const* d_in, const int* in_sizes, int n_in,
                              void* d_out, int out_size, void* d_ws, size_t ws_size,
                              hipStream_t stream) {
    (void)in_sizes; (void)n_in; (void)out_size; (void)ws_size;
    const float* x       = (const float*)d_in[0];
    const float* w_sq1   = (const float*)d_in[1];
    const float* b_sq1   = (const float*)d_in[2];
    const float* w_sq2   = (const float*)d_in[3];
    const float* b_sq2   = (const float*)d_in[4];
    const float* ca_wqkv = (const float*)d_in[5];
    const float* ca_bqkv = (const float*)d_in[6];
    const float* ca_t    = (const float*)d_in[7];
    const float* ca_wf   = (const float*)d_in[8];
    const float* ca_bf   = (const float*)d_in[9];
    const float* sa_wqkv = (const float*)d_in[10];
    const float* sa_bqkv = (const float*)d_in[11];
    const float* sa_t    = (const float*)d_in[12];
    const float* sa_wf   = (const float*)d_in[13];
    const float* sa_bf   = (const float*)d_in[14];
    const float* w_un1   = (const float*)d_in[15];
    const float* b_un1   = (const float*)d_in[16];
    const float* w_un2   = (const float*)d_in[17];
    const float* b_un2   = (const float*)d_in[18];
    float* out = (float*)d_out;
    float* ws  = (float*)d_ws;
    float* y1 = ws;                // 262144 floats (2,32,4096)
    float* y3 = ws + 262144;       // 131072 floats (2,64,1024)
    float* y4 = ws + 393216;       // 131072 floats (2,64,1024)
    float* y8 = ws;                // reuse y1 region (dead after K2): (2,32,4096)

    k_conv_sq1<<<128, 256, 0, stream>>>(x, w_sq1, b_sq1, y1);
    k_dw_perm <<<512, 256, 0, stream>>>(y1, w_sq2, b_sq2, y3);
    k_chan_attn<<<64, 256, 0, stream>>>(y3, ca_wqkv, ca_bqkv, ca_t, ca_wf, ca_bf, y4);
    k_spat_attn<<<512, 256, 0, stream>>>(y4, sa_wqkv, sa_bqkv, sa_t, sa_wf, sa_bf,
                                         w_un1, b_un1, y8);
    k_conv_un2<<<128, 256, 0, stream>>>(y8, w_un2, b_un2, out);
}

// Round 2
// 132.017 us; speedup vs baseline: 1.0854x; 1.0854x over previous
//
#include <hip/hip_runtime.h>
#include <math.h>

#define LOG2E 1.4426950408889634f

typedef float v2f __attribute__((ext_vector_type(2)));

__device__ __forceinline__ float fast_exp2(float x) {
#if defined(__has_builtin)
#if __has_builtin(__builtin_amdgcn_exp2f)
    return __builtin_amdgcn_exp2f(x);
#else
    return exp2f(x);
#endif
#else
    return exp2f(x);
#endif
}

__device__ __forceinline__ v2f vfma2(v2f a, v2f b, v2f c) {
#if defined(__has_builtin)
#if __has_builtin(__builtin_elementwise_fma)
    return __builtin_elementwise_fma(a, b, c);
#else
    v2f r; r.x = fmaf(a.x, b.x, c.x); r.y = fmaf(a.y, b.y, c.y); return r;
#endif
#else
    v2f r; r.x = fmaf(a.x, b.x, c.x); r.y = fmaf(a.y, b.y, c.y); return r;
#endif
}

// ---------------------------------------------------------------------------
// kA: fused 1x1 conv (64->32) + depthwise 2x2/s2 conv + channel permute.
// Each thread computes the 2x2 y1-patch (registers only) that feeds one
// output pixel of one dw group, then both dw output channels of that group.
// Grid: 256 = (b:2, i32:32, q:4). Block covers y3 channels [16q,16q+16),
// output row i32 (32 px). Needs x[b,:,2*i32:2*i32+2,:] = 64x128 floats.
// ---------------------------------------------------------------------------
__global__ __launch_bounds__(256) void k_front(const float* __restrict__ x,
        const float* __restrict__ w1x1, const float* __restrict__ b1x1,
        const float* __restrict__ wdw,  const float* __restrict__ bdw,
        float* __restrict__ y3) {
    __shared__ float lxs[64 * 128];   // [c][col2]
    __shared__ float lwt[8][64];      // [gidx][c]
    int tid = threadIdx.x;
    int q   = blockIdx.x & 3;
    int i32 = (blockIdx.x >> 2) & 31;
    int b   = blockIdx.x >> 7;

    // stage x rows 2*i32, 2*i32+1 (128 px) for all 64 c: 2048 float4
    const float4* x4 = (const float4*)x;
#pragma unroll
    for (int i = 0; i < 8; ++i) {
        int f4 = tid + i * 256;
        int c  = f4 >> 5, cw = f4 & 31;
        ((float4*)lxs)[f4] = x4[(b * 64 + c) * 1024 + i32 * 32 + cw];
    }
    // stage the 8 w rows this block needs
    for (int idx = tid; idx < 512; idx += 256) {
        int gi = idx >> 6, c = idx & 63;
        int g = 4 * q + (gi & 3) + ((gi & 4) << 2);
        lwt[gi][c] = w1x1[g * 64 + c];
    }
    __syncthreads();

    int gidx = tid >> 5, col = tid & 31;
    int g = 4 * q + (gidx & 3) + ((gidx & 4) << 2);
    v2f acc0 = {0.f, 0.f}, acc1 = {0.f, 0.f};
    const v2f* lx2 = (const v2f*)lxs;
#pragma unroll 4
    for (int c = 0; c < 64; ++c) {
        float wv = lwt[gidx][c];
        v2f w2 = {wv, wv};
        acc0 = vfma2(w2, lx2[c * 64 + col], acc0);
        acc1 = vfma2(w2, lx2[c * 64 + 32 + col], acc1);
    }
    float bs = b1x1[g];
    float a00 = acc0.x + bs, a01 = acc0.y + bs;
    float a10 = acc1.x + bs, a11 = acc1.y + bs;
#pragma unroll
    for (int s = 0; s < 2; ++s) {
        int oc = 2 * g + s;
        int k  = 2 * (oc & 31) + (oc >> 5);   // permuted y3 channel
        float4 wd = ((const float4*)wdw)[oc];
        float v = bdw[oc];
        v = fmaf(wd.x, a00, v); v = fmaf(wd.y, a01, v);
        v = fmaf(wd.z, a10, v); v = fmaf(wd.w, a11, v);
        y3[(b * 64 + k) * 1024 + i32 * 32 + col] = v;
    }
}

// ---------------------------------------------------------------------------
// Channel-attention collapsed map: for y3-pair p, output row d only.
// Returns A,B,C with y4[2p+d] = A*y3[2p] + B*y3[2p+1] + C  (incl. wf/bf fuse).
// ---------------------------------------------------------------------------
__device__ __forceinline__ void ca_coeffs(int p, int d,
        float s00, float s01, float s11, float m0, float m1,
        const float* __restrict__ wqkv, const float* __restrict__ bqkv,
        const float* __restrict__ t,    const float* __restrict__ wf,
        const float* __restrict__ bf,   float& A, float& B, float& C) {
    const float N = 1024.f;
    int c0 = 2 * p, c1 = 2 * p + 1;
    int c  = 2 * p + d;
    float Aa = 0.f, Bb = 0.f, Cc = 0.f;
#pragma unroll
    for (int e = 0; e < 2; ++e) {
        float wq0 = wqkv[c0 * 6 + e],     wq1 = wqkv[c1 * 6 + e];
        float bq0 = bqkv[c0 * 6 + e],     bq1 = bqkv[c1 * 6 + e];
        float wk0 = wqkv[c0 * 6 + 2 + e], wk1 = wqkv[c1 * 6 + 2 + e];
        float bk0 = bqkv[c0 * 6 + 2 + e], bk1 = bqkv[c1 * 6 + 2 + e];
        float wv0 = wqkv[c0 * 6 + 4 + e], wv1 = wqkv[c1 * 6 + 4 + e];
        float bv0 = bqkv[c0 * 6 + 4 + e], bv1 = bqkv[c1 * 6 + 4 + e];
        float te  = t[e * 32 + p];
        float sqq = (d == 0) ? (wq0 * wq0 * s00 + 2.f * wq0 * bq0 * m0 + N * bq0 * bq0)
                             : (wq1 * wq1 * s11 + 2.f * wq1 * bq1 * m1 + N * bq1 * bq1);
        float kk0 = wk0 * wk0 * s00 + 2.f * wk0 * bk0 * m0 + N * bk0 * bk0;
        float kk1 = wk1 * wk1 * s11 + 2.f * wk1 * bk1 * m1 + N * bk1 * bk1;
        float inq  = 1.f / fmaxf(sqrtf(fmaxf(sqq, 0.f)), 1e-12f);
        float ink0 = 1.f / fmaxf(sqrtf(fmaxf(kk0, 0.f)), 1e-12f);
        float ink1 = 1.f / fmaxf(sqrtf(fmaxf(kk1, 0.f)), 1e-12f);
        float qk0 = (d == 0) ? (wq0 * wk0 * s00 + wq0 * bk0 * m0 + bq0 * wk0 * m0 + N * bq0 * bk0)
                             : (wq1 * wk0 * s01 + wq1 * bk0 * m1 + bq1 * wk0 * m0 + N * bq1 * bk0);
        float qk1 = (d == 0) ? (wq0 * wk1 * s01 + wq0 * bk1 * m0 + bq0 * wk1 * m1 + N * bq0 * bk1)
                             : (wq1 * wk1 * s11 + wq1 * bk1 * m1 + bq1 * wk1 * m1 + N * bq1 * bk1);
        float L0 = qk0 * inq * ink0 * te, L1 = qk1 * inq * ink1 * te;
        float mx = fmaxf(L0, L1);
        float e0 = expf(L0 - mx), e1 = expf(L1 - mx);
        float iv = 1.f / (e0 + e1);
        float p0 = e0 * iv, p1 = e1 * iv;
        float f = wf[c * 2 + e];
        Aa += f * p0 * wv0;
        Bb += f * p1 * wv1;
        Cc += f * (p0 * bv0 + p1 * bv1);
    }
    A = Aa; B = Bb; C = Cc + bf[c];
}

// ---------------------------------------------------------------------------
// kB: channel attention (redundant per-block Gram stats) + nidx permute +
// spatial attention (rank-2 flash, packed-pair f32) + group-fuse + grouped
// 1x1 un1 + pixel shuffle. Grid: 512 = (b:2, j:32, chunk:8).
// Needed y4 channels for spatial pair j live in y3 channels 4j'..4j'+3
// (j' = j&15, d = j>>4) -- contiguous, staged once per block.
// ---------------------------------------------------------------------------
__global__ __launch_bounds__(256) void k_attn(const float* __restrict__ y3,
        const float* __restrict__ ca_wqkv, const float* __restrict__ ca_bqkv,
        const float* __restrict__ ca_t,    const float* __restrict__ ca_wf,
        const float* __restrict__ ca_bf,
        const float* __restrict__ wqkv, const float* __restrict__ bqkv,
        const float* __restrict__ t,    const float* __restrict__ wf,
        const float* __restrict__ bfuse, const float* __restrict__ w1,
        const float* __restrict__ b1,   float* __restrict__ y8) {
    __shared__ float ly[4][1024];
    __shared__ float kk[2][2048];     // pair-interleaved: [4p+{0,1}]=kh0, [4p+{2,3}]=kh1
    __shared__ float vv[2][2048];     // [4p+{0,1}]=v0, [4p+{2,3}]=v1
    __shared__ float ox[2][2][128];
    __shared__ float red[10][4];
    int tid = threadIdx.x;
    int chunk = blockIdx.x & 7;
    int j = (blockIdx.x >> 3) & 31;
    int b = blockIdx.x >> 8;
    int jp = j & 15;          // j'
    int dsel = j >> 4;
    int c0 = 2 * j, c1 = 2 * j + 1;   // spatial-space channels (sa params)

    // ---- stage 4 contiguous y3 channels + Gram stats for both ca pairs ----
    const float* base = y3 + (b * 64 + 4 * jp) * 1024;
    float sA00 = 0, sA01 = 0, sA11 = 0, mA0 = 0, mA1 = 0;
    float sB00 = 0, sB01 = 0, sB11 = 0, mB0 = 0, mB1 = 0;
#pragma unroll
    for (int r = 0; r < 4; ++r) {
        int n = tid + r * 256;
        float a0 = base[n], a1 = base[1024 + n];
        float a2 = base[2048 + n], a3 = base[3072 + n];
        ly[0][n] = a0; ly[1][n] = a1; ly[2][n] = a2; ly[3][n] = a3;
        sA00 = fmaf(a0, a0, sA00); sA01 = fmaf(a0, a1, sA01); sA11 = fmaf(a1, a1, sA11);
        mA0 += a0; mA1 += a1;
        sB00 = fmaf(a2, a2, sB00); sB01 = fmaf(a2, a3, sB01); sB11 = fmaf(a3, a3, sB11);
        mB0 += a2; mB1 += a3;
    }
#pragma unroll
    for (int off = 1; off < 64; off <<= 1) {
        sA00 += __shfl_xor(sA00, off, 64); sA01 += __shfl_xor(sA01, off, 64);
        sA11 += __shfl_xor(sA11, off, 64); mA0 += __shfl_xor(mA0, off, 64);
        mA1  += __shfl_xor(mA1,  off, 64);
        sB00 += __shfl_xor(sB00, off, 64); sB01 += __shfl_xor(sB01, off, 64);
        sB11 += __shfl_xor(sB11, off, 64); mB0 += __shfl_xor(mB0, off, 64);
        mB1  += __shfl_xor(mB1,  off, 64);
    }
    int wid = tid >> 6;
    if ((tid & 63) == 0) {
        red[0][wid] = sA00; red[1][wid] = sA01; red[2][wid] = sA11;
        red[3][wid] = mA0;  red[4][wid] = mA1;
        red[5][wid] = sB00; red[6][wid] = sB01; red[7][wid] = sB11;
        red[8][wid] = mB0;  red[9][wid] = mB1;
    }
    __syncthreads();
    sA00 = red[0][0] + red[0][1] + red[0][2] + red[0][3];
    sA01 = red[1][0] + red[1][1] + red[1][2] + red[1][3];
    sA11 = red[2][0] + red[2][1] + red[2][2] + red[2][3];
    mA0  = red[3][0] + red[3][1] + red[3][2] + red[3][3];
    mA1  = red[4][0] + red[4][1] + red[4][2] + red[4][3];
    sB00 = red[5][0] + red[5][1] + red[5][2] + red[5][3];
    sB01 = red[6][0] + red[6][1] + red[6][2] + red[6][3];
    sB11 = red[7][0] + red[7][1] + red[7][2] + red[7][3];
    mB0  = red[8][0] + red[8][1] + red[8][2] + red[8][3];
    mB1  = red[9][0] + red[9][1] + red[9][2] + red[9][3];

    // ---- channel-attn linear maps (lx0 = map(ly0,ly1), lx1 = map(ly2,ly3)) ----
    float Aa, Ba, Ca, Ab, Bb, Cb;
    ca_coeffs(2 * jp,     dsel, sA00, sA01, sA11, mA0, mA1,
              ca_wqkv, ca_bqkv, ca_t, ca_wf, ca_bf, Aa, Ba, Ca);
    ca_coeffs(2 * jp + 1, dsel, sB00, sB01, sB11, mB0, mB1,
              ca_wqkv, ca_bqkv, ca_t, ca_wf, ca_bf, Ab, Bb, Cb);

    // ---- build packed K-hat (pre-scaled t*log2e) and V ----
    float wk0e[2], wk1e[2], bk0e[2], bk1e[2], wv0e[2], wv1e[2], bv0e[2], bv1e[2], tle[2];
#pragma unroll
    for (int ee = 0; ee < 2; ++ee) {
        wk0e[ee] = wqkv[c0 * 6 + 2 + ee]; wk1e[ee] = wqkv[c1 * 6 + 2 + ee];
        bk0e[ee] = bqkv[c0 * 6 + 2 + ee]; bk1e[ee] = bqkv[c1 * 6 + 2 + ee];
        wv0e[ee] = wqkv[c0 * 6 + 4 + ee]; wv1e[ee] = wqkv[c1 * 6 + 4 + ee];
        bv0e[ee] = bqkv[c0 * 6 + 4 + ee]; bv1e[ee] = bqkv[c1 * 6 + 4 + ee];
        tle[ee]  = t[ee * 32 + j] * LOG2E;
    }
#pragma unroll
    for (int p = tid; p < 512; p += 256) {
        int m0i = 2 * p, m1i = 2 * p + 1;
        float xa0 = fmaf(Aa, ly[0][m0i], fmaf(Ba, ly[1][m0i], Ca));
        float xa1 = fmaf(Aa, ly[0][m1i], fmaf(Ba, ly[1][m1i], Ca));
        float xb0 = fmaf(Ab, ly[2][m0i], fmaf(Bb, ly[3][m0i], Cb));
        float xb1 = fmaf(Ab, ly[2][m1i], fmaf(Bb, ly[3][m1i], Cb));
#pragma unroll
        for (int ee = 0; ee < 2; ++ee) {
            float k00 = fmaf(wk0e[ee], xa0, bk0e[ee]);
            float k10 = fmaf(wk1e[ee], xb0, bk1e[ee]);
            float k01 = fmaf(wk0e[ee], xa1, bk0e[ee]);
            float k11 = fmaf(wk1e[ee], xb1, bk1e[ee]);
            float i0 = tle[ee] / fmaxf(sqrtf(k00 * k00 + k10 * k10), 1e-12f);
            float i1 = tle[ee] / fmaxf(sqrtf(k01 * k01 + k11 * k11), 1e-12f);
            *(float2*)&kk[ee][4 * p]     = make_float2(k00 * i0, k01 * i1);
            *(float2*)&kk[ee][4 * p + 2] = make_float2(k10 * i0, k11 * i1);
            *(float2*)&vv[ee][4 * p]     = make_float2(fmaf(wv0e[ee], xa0, bv0e[ee]),
                                                       fmaf(wv0e[ee], xa1, bv0e[ee]));
            *(float2*)&vv[ee][4 * p + 2] = make_float2(fmaf(wv1e[ee], xb0, bv1e[ee]),
                                                       fmaf(wv1e[ee], xb1, bv1e[ee]));
        }
    }
    __syncthreads();

    // ---- query pass: 128 n x 2 e, packed 2-key inner loop ----
    int nn = tid & 127;
    int e  = tid >> 7;                 // wave-uniform
    int n  = chunk * 128 + nn;
    float xan = fmaf(Aa, ly[0][n], fmaf(Ba, ly[1][n], Ca));
    float xbn = fmaf(Ab, ly[2][n], fmaf(Bb, ly[3][n], Cb));
    float wq0 = wqkv[c0 * 6 + e], wq1 = wqkv[c1 * 6 + e];
    float bq0 = bqkv[c0 * 6 + e], bq1 = bqkv[c1 * 6 + e];
    float tt  = t[e * 32 + j];
    float q0 = fmaf(wq0, xan, bq0), q1 = fmaf(wq1, xbn, bq1);
    float qinv = 1.f / fmaxf(sqrtf(q0 * q0 + q1 * q1), 1e-12f);
    float a = q0 * qinv, bqn = q1 * qinv;
    float cbias = -fabsf(tt) * LOG2E;   // arg <= 0, stable
    v2f av = {a, a}, bv2 = {bqn, bqn}, cb = {cbias, cbias};
    v2f den2 = {0.f, 0.f}, o02 = {0.f, 0.f}, o12 = {0.f, 0.f};
    const float4* kp = (const float4*)kk[e];
    const float4* vp = (const float4*)vv[e];
#pragma unroll 4
    for (int p = 0; p < 512; ++p) {
        float4 K = kp[p];
        float4 V = vp[p];
        v2f kx = {K.x, K.y}, ky = {K.z, K.w};
        v2f arg = vfma2(av, kx, vfma2(bv2, ky, cb));
        v2f w = {fast_exp2(arg.x), fast_exp2(arg.y)};
        den2 += w;
        v2f vz = {V.x, V.y}, vw = {V.z, V.w};
        o02 = vfma2(w, vz, o02);
        o12 = vfma2(w, vw, o12);
    }
    float den = den2.x + den2.y;
    float r = 1.f / den;
    ox[e][0][nn] = (o02.x + o02.y) * r;
    ox[e][1][nn] = (o12.x + o12.y) * r;
    __syncthreads();

    // ---- group fuse + un1 + pixel shuffle ----
    if (tid < 128) {
        int n2 = chunk * 128 + tid;
        float t0 = fmaf(wf[c0 * 2], ox[0][0][tid], fmaf(wf[c0 * 2 + 1], ox[1][0][tid], bfuse[c0]));
        float t1 = fmaf(wf[c1 * 2], ox[0][1][tid], fmaf(wf[c1 * 2 + 1], ox[1][1][tid], bfuse[c1]));
        int i32 = n2 >> 5, j32 = n2 & 31;
        float* dst = y8 + (b * 32 + j) * 4096 + (i32 * 2) * 64 + j32 * 2;
#pragma unroll
        for (int rr = 0; rr < 4; ++rr) {
            float z = fmaf(w1[(4 * j + rr) * 2], t0,
                      fmaf(w1[(4 * j + rr) * 2 + 1], t1, b1[4 * j + rr]));
            dst[(rr >> 1) * 64 + (rr & 1)] = z;
        }
    }
}

// ---------------------------------------------------------------------------
// kC: out[b,o,p] = sum_g w_un2[o,g]*y8[b,g,p] + b_un2[o];  (2,64,4096)
// ---------------------------------------------------------------------------
__global__ __launch_bounds__(256) void k_conv_un2(const float* __restrict__ y8,
        const float* __restrict__ w, const float* __restrict__ bias,
        float* __restrict__ out) {
    __shared__ float lx[32 * 64];   // [g][px]
    __shared__ float lw[64 * 32];   // [o][g]
    int tid = threadIdx.x;
    int gp0 = blockIdx.x * 64;
    int b = gp0 >> 12;
    int p0 = gp0 & 4095;
    for (int idx = tid; idx < 32 * 64; idx += 256) {
        int g = idx >> 6, pp = idx & 63;
        lx[idx] = y8[(b * 32 + g) * 4096 + p0 + pp];
    }
    for (int idx = tid; idx < 64 * 32; idx += 256) lw[idx] = w[idx];
    __syncthreads();
    int px = tid & 63, og = tid >> 6;   // 16 outputs each
    float acc[16];
#pragma unroll
    for (int k = 0; k < 16; ++k) acc[k] = 0.f;
    for (int g = 0; g < 32; ++g) {
        float xv = lx[g * 64 + px];
#pragma unroll
        for (int k = 0; k < 16; ++k)
            acc[k] = fmaf(lw[(og * 16 + k) * 32 + g], xv, acc[k]);
    }
#pragma unroll
    for (int k = 0; k < 16; ++k) {
        int o = og * 16 + k;
        out[(b * 64 + o) * 4096 + p0 + px] = acc[k] + bias[o];
    }
}

extern "C" void kernel_launch(void* const* d_in, const int* in_sizes, int n_in,
                              void* d_out, int out_size, void* d_ws, size_t ws_size,
                              hipStream_t stream) {
    (void)in_sizes; (void)n_in; (void)out_size; (void)ws_size;
    const float* x       = (const float*)d_in[0];
    const float* w_sq1   = (const float*)d_in[1];
    const float* b_sq1   = (const float*)d_in[2];
    const float* w_sq2   = (const float*)d_in[3];
    const float* b_sq2   = (const float*)d_in[4];
    const float* ca_wqkv = (const float*)d_in[5];
    const float* ca_bqkv = (const float*)d_in[6];
    const float* ca_t    = (const float*)d_in[7];
    const float* ca_wf   = (const float*)d_in[8];
    const float* ca_bf   = (const float*)d_in[9];
    const float* sa_wqkv = (const float*)d_in[10];
    const float* sa_bqkv = (const float*)d_in[11];
    const float* sa_t    = (const float*)d_in[12];
    const float* sa_wf   = (const float*)d_in[13];
    const float* sa_bf   = (const float*)d_in[14];
    const float* w_un1   = (const float*)d_in[15];
    const float* b_un1   = (const float*)d_in[16];
    const float* w_un2   = (const float*)d_in[17];
    const float* b_un2   = (const float*)d_in[18];
    float* out = (float*)d_out;
    float* ws  = (float*)d_ws;
    float* y3 = ws;                 // (2,64,1024)  = 131072 floats
    float* y8 = ws + 131072;        // (2,32,64,64) = 262144 floats

    k_front<<<256, 256, 0, stream>>>(x, w_sq1, b_sq1, w_sq2, b_sq2, y3);
    k_attn <<<512, 256, 0, stream>>>(y3, ca_wqkv, ca_bqkv, ca_t, ca_wf, ca_bf,
                                     sa_wqkv, sa_bqkv, sa_t, sa_wf, sa_bf,
                                     w_un1, b_un1, y8);
    k_conv_un2<<<128, 256, 0, stream>>>(y8, w_un2, b_un2, out);
}

// Round 3
// 111.311 us; speedup vs baseline: 1.2873x; 1.1860x over previous
//
#include <hip/hip_runtime.h>
#include <math.h>

#define NR 8   // Fourier terms r=1..NR; trunc error ~I_{NR+1}(t): 5e-10 at t=1

typedef float v2f __attribute__((ext_vector_type(2)));

__device__ __forceinline__ v2f vfma2(v2f a, v2f b, v2f c) {
#if defined(__has_builtin)
#if __has_builtin(__builtin_elementwise_fma)
    return __builtin_elementwise_fma(a, b, c);
#else
    v2f r; r.x = fmaf(a.x, b.x, c.x); r.y = fmaf(a.y, b.y, c.y); return r;
#endif
#else
    v2f r; r.x = fmaf(a.x, b.x, c.x); r.y = fmaf(a.y, b.y, c.y); return r;
#endif
}

// J[r] = (r==0 ? 1 : 2) * I_r(t), modified Bessel, series (all divisors fold
// to compile-time reciprocal multiplies after full unroll).
__device__ __forceinline__ void bessel_J(float t, float* J) {
    float h = 0.5f * t, q = h * h;
    float hp = 1.f;   // h^r
    float rf = 1.f;   // 1/r!
#pragma unroll
    for (int r = 0; r <= NR; ++r) {
        if (r > 0) { hp *= h; rf *= (1.f / r); }
        float term = hp * rf;
        float sum = term;
#pragma unroll
        for (int k = 1; k <= 12; ++k) {
            term *= q * (1.f / (k * (r + k)));
            sum += term;
        }
        J[r] = (r ? 2.f : 1.f) * sum;
    }
}

// ---------------------------------------------------------------------------
// kA: fused 1x1 conv (64->32) + depthwise 2x2/s2 conv + channel permute.
// Grid: 256 = (b:2, i32:32, q:4).
// ---------------------------------------------------------------------------
__global__ __launch_bounds__(256) void k_front(const float* __restrict__ x,
        const float* __restrict__ w1x1, const float* __restrict__ b1x1,
        const float* __restrict__ wdw,  const float* __restrict__ bdw,
        float* __restrict__ y3) {
    __shared__ float lxs[64 * 128];   // [c][col2]
    __shared__ float lwt[8][64];      // [gidx][c]
    int tid = threadIdx.x;
    int q   = blockIdx.x & 3;
    int i32 = (blockIdx.x >> 2) & 31;
    int b   = blockIdx.x >> 7;

    const float4* x4 = (const float4*)x;
#pragma unroll
    for (int i = 0; i < 8; ++i) {
        int f4 = tid + i * 256;
        int c  = f4 >> 5, cw = f4 & 31;
        ((float4*)lxs)[f4] = x4[(b * 64 + c) * 1024 + i32 * 32 + cw];
    }
    for (int idx = tid; idx < 512; idx += 256) {
        int gi = idx >> 6, c = idx & 63;
        int g = 4 * q + (gi & 3) + ((gi & 4) << 2);
        lwt[gi][c] = w1x1[g * 64 + c];
    }
    __syncthreads();

    int gidx = tid >> 5, col = tid & 31;
    int g = 4 * q + (gidx & 3) + ((gidx & 4) << 2);
    v2f acc0 = {0.f, 0.f}, acc1 = {0.f, 0.f};
    const v2f* lx2 = (const v2f*)lxs;
#pragma unroll 4
    for (int c = 0; c < 64; ++c) {
        float wv = lwt[gidx][c];
        v2f w2 = {wv, wv};
        acc0 = vfma2(w2, lx2[c * 64 + col], acc0);
        acc1 = vfma2(w2, lx2[c * 64 + 32 + col], acc1);
    }
    float bs = b1x1[g];
    float a00 = acc0.x + bs, a01 = acc0.y + bs;
    float a10 = acc1.x + bs, a11 = acc1.y + bs;
#pragma unroll
    for (int s = 0; s < 2; ++s) {
        int oc = 2 * g + s;
        int k  = 2 * (oc & 31) + (oc >> 5);   // permuted y3 channel
        float4 wd = ((const float4*)wdw)[oc];
        float v = bdw[oc];
        v = fmaf(wd.x, a00, v); v = fmaf(wd.y, a01, v);
        v = fmaf(wd.z, a10, v); v = fmaf(wd.w, a11, v);
        y3[(b * 64 + k) * 1024 + i32 * 32 + col] = v;
    }
}

// ---------------------------------------------------------------------------
// Channel-attention collapsed map (exact): y4[2p+d] = A*y3[2p]+B*y3[2p+1]+C.
// ---------------------------------------------------------------------------
__device__ __forceinline__ void ca_coeffs(int p, int d,
        float s00, float s01, float s11, float m0, float m1,
        const float* __restrict__ wqkv, const float* __restrict__ bqkv,
        const float* __restrict__ t,    const float* __restrict__ wf,
        const float* __restrict__ bf,   float& A, float& B, float& C) {
    const float N = 1024.f;
    int c0 = 2 * p, c1 = 2 * p + 1;
    int c  = 2 * p + d;
    float Aa = 0.f, Bb = 0.f, Cc = 0.f;
#pragma unroll
    for (int e = 0; e < 2; ++e) {
        float wq0 = wqkv[c0 * 6 + e],     wq1 = wqkv[c1 * 6 + e];
        float bq0 = bqkv[c0 * 6 + e],     bq1 = bqkv[c1 * 6 + e];
        float wk0 = wqkv[c0 * 6 + 2 + e], wk1 = wqkv[c1 * 6 + 2 + e];
        float bk0 = bqkv[c0 * 6 + 2 + e], bk1 = bqkv[c1 * 6 + 2 + e];
        float wv0 = wqkv[c0 * 6 + 4 + e], wv1 = wqkv[c1 * 6 + 4 + e];
        float bv0 = bqkv[c0 * 6 + 4 + e], bv1 = bqkv[c1 * 6 + 4 + e];
        float te  = t[e * 32 + p];
        float sqq = (d == 0) ? (wq0 * wq0 * s00 + 2.f * wq0 * bq0 * m0 + N * bq0 * bq0)
                             : (wq1 * wq1 * s11 + 2.f * wq1 * bq1 * m1 + N * bq1 * bq1);
        float kk0 = wk0 * wk0 * s00 + 2.f * wk0 * bk0 * m0 + N * bk0 * bk0;
        float kk1 = wk1 * wk1 * s11 + 2.f * wk1 * bk1 * m1 + N * bk1 * bk1;
        float inq  = 1.f / fmaxf(sqrtf(fmaxf(sqq, 0.f)), 1e-12f);
        float ink0 = 1.f / fmaxf(sqrtf(fmaxf(kk0, 0.f)), 1e-12f);
        float ink1 = 1.f / fmaxf(sqrtf(fmaxf(kk1, 0.f)), 1e-12f);
        float qk0 = (d == 0) ? (wq0 * wk0 * s00 + wq0 * bk0 * m0 + bq0 * wk0 * m0 + N * bq0 * bk0)
                             : (wq1 * wk0 * s01 + wq1 * bk0 * m1 + bq1 * wk0 * m0 + N * bq1 * bk0);
        float qk1 = (d == 0) ? (wq0 * wk1 * s01 + wq0 * bk1 * m0 + bq0 * wk1 * m1 + N * bq0 * bk1)
                             : (wq1 * wk1 * s11 + wq1 * bk1 * m1 + bq1 * wk1 * m1 + N * bq1 * bk1);
        float L0 = qk0 * inq * ink0 * te, L1 = qk1 * inq * ink1 * te;
        float mx = fmaxf(L0, L1);
        float e0 = expf(L0 - mx), e1 = expf(L1 - mx);
        float iv = 1.f / (e0 + e1);
        float p0 = e0 * iv, p1 = e1 * iv;
        float f = wf[c * 2 + e];
        Aa += f * p0 * wv0;
        Bb += f * p1 * wv1;
        Cc += f * (p0 * bv0 + p1 * bv1);
    }
    A = Aa; B = Bb; C = Cc + bf[c];
}

// ---------------------------------------------------------------------------
// kB: channel attention (collapsed) + nidx permute + spatial attention via
// rank-2 Fourier/Bessel moment expansion (O(N+M), no score loop!) + group
// fuse + grouped 1x1 un1 + pixel shuffle.
// Grid: 256 = (b:2, j:32, chunk:4); 256 threads.
//   phase2: threads split by e (tid>>7); each thread accumulates 54 moments
//           Sum_m {1,v0,v1} x {cos,sin}(r*phi_m), r=0..8, over 8 keys.
//   phase3: each thread = 1 query n, both e; den/o from moment dot products.
// ---------------------------------------------------------------------------
__global__ __launch_bounds__(256) void k_attn(const float* __restrict__ y3,
        const float* __restrict__ ca_wqkv, const float* __restrict__ ca_bqkv,
        const float* __restrict__ ca_t,    const float* __restrict__ ca_wf,
        const float* __restrict__ ca_bf,
        const float* __restrict__ wqkv, const float* __restrict__ bqkv,
        const float* __restrict__ t,    const float* __restrict__ wf,
        const float* __restrict__ bfuse, const float* __restrict__ w1,
        const float* __restrict__ b1,   float* __restrict__ y8) {
    __shared__ float ly[4][1024];
    __shared__ float redg[10][4];
    __shared__ float redm[4][54];
    __shared__ float momf[2][54];
    int tid = threadIdx.x;
    int chunk = blockIdx.x & 3;
    int j = (blockIdx.x >> 2) & 31;
    int b = blockIdx.x >> 7;
    int jp = j & 15;
    int dsel = j >> 4;
    int c0 = 2 * j, c1 = 2 * j + 1;

    // ---- phase 1: stage 4 y3 channels + Gram stats for both ca pairs ----
    const float* base = y3 + (b * 64 + 4 * jp) * 1024;
    float sA00 = 0, sA01 = 0, sA11 = 0, mA0 = 0, mA1 = 0;
    float sB00 = 0, sB01 = 0, sB11 = 0, mB0 = 0, mB1 = 0;
#pragma unroll
    for (int r = 0; r < 4; ++r) {
        int n = tid + r * 256;
        float a0 = base[n], a1 = base[1024 + n];
        float a2 = base[2048 + n], a3 = base[3072 + n];
        ly[0][n] = a0; ly[1][n] = a1; ly[2][n] = a2; ly[3][n] = a3;
        sA00 = fmaf(a0, a0, sA00); sA01 = fmaf(a0, a1, sA01); sA11 = fmaf(a1, a1, sA11);
        mA0 += a0; mA1 += a1;
        sB00 = fmaf(a2, a2, sB00); sB01 = fmaf(a2, a3, sB01); sB11 = fmaf(a3, a3, sB11);
        mB0 += a2; mB1 += a3;
    }
#pragma unroll
    for (int off = 1; off < 64; off <<= 1) {
        sA00 += __shfl_xor(sA00, off, 64); sA01 += __shfl_xor(sA01, off, 64);
        sA11 += __shfl_xor(sA11, off, 64); mA0 += __shfl_xor(mA0, off, 64);
        mA1  += __shfl_xor(mA1,  off, 64);
        sB00 += __shfl_xor(sB00, off, 64); sB01 += __shfl_xor(sB01, off, 64);
        sB11 += __shfl_xor(sB11, off, 64); mB0 += __shfl_xor(mB0, off, 64);
        mB1  += __shfl_xor(mB1,  off, 64);
    }
    int wid = tid >> 6;
    if ((tid & 63) == 0) {
        redg[0][wid] = sA00; redg[1][wid] = sA01; redg[2][wid] = sA11;
        redg[3][wid] = mA0;  redg[4][wid] = mA1;
        redg[5][wid] = sB00; redg[6][wid] = sB01; redg[7][wid] = sB11;
        redg[8][wid] = mB0;  redg[9][wid] = mB1;
    }
    __syncthreads();
    sA00 = redg[0][0] + redg[0][1] + redg[0][2] + redg[0][3];
    sA01 = redg[1][0] + redg[1][1] + redg[1][2] + redg[1][3];
    sA11 = redg[2][0] + redg[2][1] + redg[2][2] + redg[2][3];
    mA0  = redg[3][0] + redg[3][1] + redg[3][2] + redg[3][3];
    mA1  = redg[4][0] + redg[4][1] + redg[4][2] + redg[4][3];
    sB00 = redg[5][0] + redg[5][1] + redg[5][2] + redg[5][3];
    sB01 = redg[6][0] + redg[6][1] + redg[6][2] + redg[6][3];
    sB11 = redg[7][0] + redg[7][1] + redg[7][2] + redg[7][3];
    mB0  = redg[8][0] + redg[8][1] + redg[8][2] + redg[8][3];
    mB1  = redg[9][0] + redg[9][1] + redg[9][2] + redg[9][3];

    float Aa, Ba, Ca, Ab, Bb, Cb;
    ca_coeffs(2 * jp,     dsel, sA00, sA01, sA11, mA0, mA1,
              ca_wqkv, ca_bqkv, ca_t, ca_wf, ca_bf, Aa, Ba, Ca);
    ca_coeffs(2 * jp + 1, dsel, sB00, sB01, sB11, mB0, mB1,
              ca_wqkv, ca_bqkv, ca_t, ca_wf, ca_bf, Ab, Bb, Cb);

    // ---- phase 2: key moments (thread-half e2, 8 keys each) ----
    int e2 = tid >> 7, l = tid & 127;
    float wk0 = wqkv[c0 * 6 + 2 + e2], wk1 = wqkv[c1 * 6 + 2 + e2];
    float bk0 = bqkv[c0 * 6 + 2 + e2], bk1 = bqkv[c1 * 6 + 2 + e2];
    float wv0 = wqkv[c0 * 6 + 4 + e2], wv1 = wqkv[c1 * 6 + 4 + e2];
    float bv0 = bqkv[c0 * 6 + 4 + e2], bv1 = bqkv[c1 * 6 + 4 + e2];
    float mom[54];
#pragma unroll
    for (int i = 0; i < 54; ++i) mom[i] = 0.f;
#pragma unroll
    for (int kk = 0; kk < 8; ++kk) {
        int m = l + (kk << 7);
        float xa = fmaf(Aa, ly[0][m], fmaf(Ba, ly[1][m], Ca));
        float xb = fmaf(Ab, ly[2][m], fmaf(Bb, ly[3][m], Cb));
        float k0 = fmaf(wk0, xa, bk0), k1 = fmaf(wk1, xb, bk1);
        float inv = 1.f / fmaxf(sqrtf(k0 * k0 + k1 * k1), 1e-12f);
        float cp = k0 * inv, sp = k1 * inv;
        float v0 = fmaf(wv0, xa, bv0), v1 = fmaf(wv1, xb, bv1);
        mom[0] += 1.f; mom[1] += v0; mom[2] += v1;
        float c_m1 = 1.f, s_m1 = 0.f, c_r = cp, s_r = sp;
        float twoc = 2.f * cp;
#pragma unroll
        for (int r = 1; r <= NR; ++r) {
            mom[r * 6 + 0] += c_r;
            mom[r * 6 + 1] = fmaf(c_r, v0, mom[r * 6 + 1]);
            mom[r * 6 + 2] = fmaf(c_r, v1, mom[r * 6 + 2]);
            mom[r * 6 + 3] += s_r;
            mom[r * 6 + 4] = fmaf(s_r, v0, mom[r * 6 + 4]);
            mom[r * 6 + 5] = fmaf(s_r, v1, mom[r * 6 + 5]);
            float cn = fmaf(twoc, c_r, -c_m1);
            float sn = fmaf(twoc, s_r, -s_m1);
            c_m1 = c_r; s_m1 = s_r; c_r = cn; s_r = sn;
        }
    }
#pragma unroll
    for (int i = 0; i < 54; ++i) {
        float v = mom[i];
        v += __shfl_xor(v, 1, 64);  v += __shfl_xor(v, 2, 64);
        v += __shfl_xor(v, 4, 64);  v += __shfl_xor(v, 8, 64);
        v += __shfl_xor(v, 16, 64); v += __shfl_xor(v, 32, 64);
        mom[i] = v;
    }
    if ((tid & 63) == 0) {
#pragma unroll
        for (int i = 0; i < 54; ++i) redm[wid][i] = mom[i];
    }
    __syncthreads();
    if (tid < 108) {
        int e = (tid >= 54) ? 1 : 0;
        int i = tid - 54 * e;
        int r = i / 6;
        float J[NR + 1];
        bessel_J(t[e * 32 + j], J);
        momf[e][i] = (redm[2 * e][i] + redm[2 * e + 1][i]) * J[r];
    }
    __syncthreads();

    // ---- phase 3: queries (1 per thread, both e) ----
    int n = (chunk << 8) + tid;
    float xan = fmaf(Aa, ly[0][n], fmaf(Ba, ly[1][n], Ca));
    float xbn = fmaf(Ab, ly[2][n], fmaf(Bb, ly[3][n], Cb));
    float oo[2][2];
#pragma unroll
    for (int e = 0; e < 2; ++e) {
        float wq0 = wqkv[c0 * 6 + e], wq1 = wqkv[c1 * 6 + e];
        float bq0 = bqkv[c0 * 6 + e], bq1 = bqkv[c1 * 6 + e];
        float q0 = fmaf(wq0, xan, bq0), q1 = fmaf(wq1, xbn, bq1);
        float qi = 1.f / fmaxf(sqrtf(q0 * q0 + q1 * q1), 1e-12f);
        float a = q0 * qi, bq = q1 * qi;
        float den = momf[e][0], o0 = momf[e][1], o1 = momf[e][2];
        float c_m1 = 1.f, s_m1 = 0.f, c_r = a, s_r = bq;
        float twoc = 2.f * a;
#pragma unroll
        for (int r = 1; r <= NR; ++r) {
            den = fmaf(c_r, momf[e][r * 6 + 0], den);
            o0  = fmaf(c_r, momf[e][r * 6 + 1], o0);
            o1  = fmaf(c_r, momf[e][r * 6 + 2], o1);
            den = fmaf(s_r, momf[e][r * 6 + 3], den);
            o0  = fmaf(s_r, momf[e][r * 6 + 4], o0);
            o1  = fmaf(s_r, momf[e][r * 6 + 5], o1);
            float cn = fmaf(twoc, c_r, -c_m1);
            float sn = fmaf(twoc, s_r, -s_m1);
            c_m1 = c_r; s_m1 = s_r; c_r = cn; s_r = sn;
        }
        float rr = 1.f / den;
        oo[e][0] = o0 * rr;
        oo[e][1] = o1 * rr;
    }
    // ---- epilogue: group fuse + un1 + pixel shuffle ----
    float t0 = fmaf(wf[c0 * 2], oo[0][0], fmaf(wf[c0 * 2 + 1], oo[1][0], bfuse[c0]));
    float t1 = fmaf(wf[c1 * 2], oo[0][1], fmaf(wf[c1 * 2 + 1], oo[1][1], bfuse[c1]));
    int i32 = n >> 5, j32 = n & 31;
    float* dst = y8 + (b * 32 + j) * 4096 + (i32 * 2) * 64 + j32 * 2;
    float z0 = fmaf(w1[(4 * j + 0) * 2], t0, fmaf(w1[(4 * j + 0) * 2 + 1], t1, b1[4 * j + 0]));
    float z1 = fmaf(w1[(4 * j + 1) * 2], t0, fmaf(w1[(4 * j + 1) * 2 + 1], t1, b1[4 * j + 1]));
    float z2 = fmaf(w1[(4 * j + 2) * 2], t0, fmaf(w1[(4 * j + 2) * 2 + 1], t1, b1[4 * j + 2]));
    float z3 = fmaf(w1[(4 * j + 3) * 2], t0, fmaf(w1[(4 * j + 3) * 2 + 1], t1, b1[4 * j + 3]));
    *(float2*)(dst)      = make_float2(z0, z1);
    *(float2*)(dst + 64) = make_float2(z2, z3);
}

// ---------------------------------------------------------------------------
// kC: out[b,o,p] = sum_g w_un2[o,g]*y8[b,g,p] + b_un2[o];  (2,64,4096)
// ---------------------------------------------------------------------------
__global__ __launch_bounds__(256) void k_conv_un2(const float* __restrict__ y8,
        const float* __restrict__ w, const float* __restrict__ bias,
        float* __restrict__ out) {
    __shared__ float lx[32 * 64];
    __shared__ float lw[64 * 32];
    int tid = threadIdx.x;
    int gp0 = blockIdx.x * 64;
    int b = gp0 >> 12;
    int p0 = gp0 & 4095;
    for (int idx = tid; idx < 32 * 64; idx += 256) {
        int g = idx >> 6, pp = idx & 63;
        lx[idx] = y8[(b * 32 + g) * 4096 + p0 + pp];
    }
    for (int idx = tid; idx < 64 * 32; idx += 256) lw[idx] = w[idx];
    __syncthreads();
    int px = tid & 63, og = tid >> 6;
    float acc[16];
#pragma unroll
    for (int k = 0; k < 16; ++k) acc[k] = 0.f;
    for (int g = 0; g < 32; ++g) {
        float xv = lx[g * 64 + px];
#pragma unroll
        for (int k = 0; k < 16; ++k)
            acc[k] = fmaf(lw[(og * 16 + k) * 32 + g], xv, acc[k]);
    }
#pragma unroll
    for (int k = 0; k < 16; ++k) {
        int o = og * 16 + k;
        out[(b * 64 + o) * 4096 + p0 + px] = acc[k] + bias[o];
    }
}

extern "C" void kernel_launch(void* const* d_in, const int* in_sizes, int n_in,
                              void* d_out, int out_size, void* d_ws, size_t ws_size,
                              hipStream_t stream) {
    (void)in_sizes; (void)n_in; (void)out_size; (void)ws_size;
    const float* x       = (const float*)d_in[0];
    const float* w_sq1   = (const float*)d_in[1];
    const float* b_sq1   = (const float*)d_in[2];
    const float* w_sq2   = (const float*)d_in[3];
    const float* b_sq2   = (const float*)d_in[4];
    const float* ca_wqkv = (const float*)d_in[5];
    const float* ca_bqkv = (const float*)d_in[6];
    const float* ca_t    = (const float*)d_in[7];
    const float* ca_wf   = (const float*)d_in[8];
    const float* ca_bf   = (const float*)d_in[9];
    const float* sa_wqkv = (const float*)d_in[10];
    const float* sa_bqkv = (const float*)d_in[11];
    const float* sa_t    = (const float*)d_in[12];
    const float* sa_wf   = (const float*)d_in[13];
    const float* sa_bf   = (const float*)d_in[14];
    const float* w_un1   = (const float*)d_in[15];
    const float* b_un1   = (const float*)d_in[16];
    const float* w_un2   = (const float*)d_in[17];
    const float* b_un2   = (const float*)d_in[18];
    float* out = (float*)d_out;
    float* ws  = (float*)d_ws;
    float* y3 = ws;                 // (2,64,1024)  = 131072 floats
    float* y8 = ws + 131072;        // (2,32,64,64) = 262144 floats

    k_front<<<256, 256, 0, stream>>>(x, w_sq1, b_sq1, w_sq2, b_sq2, y3);
    k_attn <<<256, 256, 0, stream>>>(y3, ca_wqkv, ca_bqkv, ca_t, ca_wf, ca_bf,
                                     sa_wqkv, sa_bqkv, sa_t, sa_wf, sa_bf,
                                     w_un1, b_un1, y8);
    k_conv_un2<<<128, 256, 0, stream>>>(y8, w_un2, b_un2, out);
}